// Round 7
// baseline (64.908 us; speedup 1.0000x reference)
//
#include <hip/hip_runtime.h>
#include <hip/hip_bf16.h>
#include <math.h>

typedef __attribute__((ext_vector_type(8))) short bf16x8;
typedef __attribute__((ext_vector_type(4))) float f32x4;
typedef unsigned short ushort_t;

#define NP 14400     // patches per video
#define NS 5         // column segments
#define NIT 45       // 64-col tiles per segment (45*64 = 2880 cols)
#define TILEB 12288  // bytes per 64-col tile (64 cols * 96 k * 2B)

__device__ __forceinline__ ushort_t f2bf(float f) {
  unsigned u = __float_as_uint(f);
  u += 0x7FFF + ((u >> 16) & 1);   // RNE
  return (ushort_t)(u >> 16);
}
__device__ __forceinline__ float bf2f(ushort_t b) {
  return __uint_as_float(((unsigned)b) << 16);
}

// Fragment-order layouts (16B chunks laid out so consumer reads are
// base + lane*16 + imm — fully coalesced, conflict-free):
// K: chunk = ((p>>6)*12 + ((p>>4)&3)*3 + (d>>5))*64 + ((d>>3)&3)*16 + (p&15)
// Q: chunk = ((p>>4)*3 + (d>>5))*64 + ((d>>3)&3)*16 + (p&15)
__device__ __forceinline__ size_t kidx(int p, int d) {
  return ((size_t)(((p >> 6) * 12 + ((p >> 4) & 3) * 3 + (d >> 5)) * 64
          + ((d >> 3) & 3) * 16 + (p & 15))) * 8 + (d & 7);
}
__device__ __forceinline__ size_t qidx(int p, int d) {
  return ((size_t)(((p >> 4) * 3 + (d >> 5)) * 64
          + ((d >> 3) & 3) * 16 + (p & 15))) * 8 + (d & 7);
}

// ---------------- prep: patches -> bf16 in fragment order -----------------
// Q: slots 0..74 = bf16(-2*q), 75,76 = 1.0, rest 0; qn = fp32 norm.
// K: slots 0..74 = bf16(k), 75 = bf16(kn), 76 = bf16(kn residual), rest 0.
// Also inits rminb to ordered-uint +inf (0xFFFFFFFF).
__global__ __launch_bounds__(256) void prep_kernel(
    const float* __restrict__ resv, const float* __restrict__ valv,
    ushort_t* __restrict__ Qb, ushort_t* __restrict__ Kb,
    float* __restrict__ qn, unsigned* __restrict__ rminb) {
  int w = threadIdx.x >> 6;
  int lane = threadIdx.x & 63;
  int pg = blockIdx.x * 4 + w;          // 0..28799
  int isK = pg >= NP;
  int p = isK ? pg - NP : pg;
  const float* src = isK ? valv : resv;
  int t = p / 3600; int rem = p - t * 3600;
  int y = rem / 60;  int x = rem - y * 60;

  float v0, v1 = 0.f;
  {
    int d = lane;  // < 75 always
    int c = d / 25; int r = d - c * 25; int dy = r / 5; int dx = r - dy * 5;
    v0 = src[((c * 4 + t) * 64 + (y + dy)) * 64 + (x + dx)];
  }
  if (lane < 11) {
    int d = lane + 64;
    int c = d / 25; int r = d - c * 25; int dy = r / 5; int dx = r - dy * 5;
    v1 = src[((c * 4 + t) * 64 + (y + dy)) * 64 + (x + dx)];
  }
  ushort_t b0 = f2bf(v0), b1 = f2bf(v1);
  float f0 = bf2f(b0), f1 = bf2f(b1);

  float sq = f0 * f0 + f1 * f1;
  #pragma unroll
  for (int off = 1; off < 64; off <<= 1) sq += __shfl_xor(sq, off, 64);

  if (isK) {
    ushort_t khi = f2bf(sq);
    ushort_t klo = f2bf(sq - bf2f(khi));
    ushort_t s1 = (lane < 11) ? b1
                : (lane == 11 ? khi : (lane == 12 ? klo : (ushort_t)0));
    Kb[kidx(p, lane)] = b0;
    if (lane < 32) Kb[kidx(p, lane + 64)] = s1;
  } else {
    ushort_t s0 = f2bf(-2.f * f0);
    ushort_t s1 = (lane < 11) ? f2bf(-2.f * f1)
                : ((lane == 11 || lane == 12) ? (ushort_t)0x3F80 : (ushort_t)0);
    Qb[qidx(p, lane)] = s0;
    if (lane < 32) Qb[qidx(p, lane + 64)] = s1;
    if (lane == 0) { qn[p] = sq; rminb[p] = 0xFFFFFFFFu; }
  }
}

// ------- main: wave-private 64x16 tiles, B streamed straight to VGPRs -----
__global__ __launch_bounds__(256, 4) void knn_kernel(
    const ushort_t* __restrict__ Qb, const ushort_t* __restrict__ Kb,
    unsigned* __restrict__ rminb) {
  // XCD-bijective swizzle: 1125 blocks, q=140 r=5; lin is ns-major so each
  // XCD sees one 0.55MB key segment + ~141 consecutive 64-row A blocks.
  int b = blockIdx.x;
  int xcd = b & 7, pos = b >> 3;
  int lin = (xcd < 5 ? xcd * 141 : 705 + (xcd - 5) * 140) + pos;
  int ns = lin / 225, rowblk = lin - ns * 225;
  int brow = rowblk * 64;
  int lane = threadIdx.x & 63;
  int w = threadIdx.x >> 6;
  int l15 = lane & 15, l4 = lane >> 4;

  // B stream base: fragment-order Kb; wave's 16-col slice of each 64-col
  // tile is 3 contiguous 1KB chunks (lane-contiguous 16B each).
  const char* gW = (const char*)Kb + (size_t)(ns * 45) * TILEB
                   + w * 3072 + lane * 16;

  // A fragments: 64 rows x 96 k, fragment-order Qb, lane-contiguous loads
  const char* Aw = (const char*)Qb + (size_t)(brow >> 4) * 3072 + lane * 16;
  bf16x8 af[4][3];
  #pragma unroll
  for (int rt = 0; rt < 4; ++rt)
    #pragma unroll
    for (int ks = 0; ks < 3; ++ks)
      af[rt][ks] = *(const bf16x8*)(Aw + (rt * 3 + ks) * 1024);

  float rmin[4][4];
  #pragma unroll
  for (int rt = 0; rt < 4; ++rt)
    #pragma unroll
    for (int j = 0; j < 4; ++j) rmin[rt][j] = INFINITY;

  const f32x4 fz = {0.f, 0.f, 0.f, 0.f};

  // depth-3 register rotation; all indices literal at every call site
  bf16x8 bbuf[3][3];

  auto loadB = [&](int bi, int it) {   // bi literal at call sites
    const char* g = gW + (size_t)it * TILEB;
    #pragma unroll
    for (int ks = 0; ks < 3; ++ks)
      bbuf[bi][ks] = *(const bf16x8*)(g + ks * 1024);
  };

  auto compute = [&](int bi) {         // bi literal at call sites
    f32x4 acc[4];
    {
      bf16x8 bv = bbuf[bi][0];
      #pragma unroll
      for (int rt = 0; rt < 4; ++rt)
        acc[rt] = __builtin_amdgcn_mfma_f32_16x16x32_bf16(af[rt][0], bv, fz, 0, 0, 0);
    }
    #pragma unroll
    for (int ks = 1; ks < 3; ++ks) {
      bf16x8 bv = bbuf[bi][ks];
      #pragma unroll
      for (int rt = 0; rt < 4; ++rt)
        acc[rt] = __builtin_amdgcn_mfma_f32_16x16x32_bf16(af[rt][ks], bv, acc[rt], 0, 0, 0);
    }
    #pragma unroll
    for (int rt = 0; rt < 4; ++rt)
      #pragma unroll
      for (int j = 0; j < 4; ++j)
        rmin[rt][j] = fminf(rmin[rt][j], acc[rt][j]);
  };

  loadB(0, 0);
  loadB(1, 1);

  // main loop: loads issued 2 iters ahead; compiler inserts minimal vmcnt
  int k = 0;
  #pragma unroll 1
  for (int tri = 0; tri < 14; ++tri, k += 3) {
    loadB(2, k + 2); compute(0);
    loadB(0, k + 3); compute(1);
    loadB(1, k + 4); compute(2);
  }
  // k == 42
  loadB(2, 44); compute(0);
  compute(1);
  compute(2);

  // min over the 16 key-cols (l15 lanes), then device atomicMin per row
  #pragma unroll
  for (int rt = 0; rt < 4; ++rt)
    #pragma unroll
    for (int j = 0; j < 4; ++j) {
      float m = rmin[rt][j];
      m = fminf(m, __shfl_xor(m, 1, 64));
      m = fminf(m, __shfl_xor(m, 2, 64));
      m = fminf(m, __shfl_xor(m, 4, 64));
      m = fminf(m, __shfl_xor(m, 8, 64));
      if (l15 == 0) {
        unsigned bu = __float_as_uint(m);
        unsigned tu = bu ^ (unsigned)(((int)bu >> 31) | (int)0x80000000);
        atomicMin(&rminb[brow + rt * 16 + l4 * 4 + j], tu);
      }
    }
}

// ---------------- final: untransform + add qn + deterministic sum ---------
__global__ __launch_bounds__(1024) void final_kernel(
    const unsigned* __restrict__ rminb, const float* __restrict__ qn,
    float* __restrict__ out) {
  int t = threadIdx.x;
  float s = 0.f;
  for (int i = t; i < NP; i += 1024) {
    unsigned u = rminb[i];
    unsigned bu = (u & 0x80000000u) ? (u ^ 0x80000000u) : ~u;
    s += __uint_as_float(bu) + qn[i];
  }
  #pragma unroll
  for (int off = 32; off; off >>= 1) s += __shfl_down(s, off, 64);
  __shared__ float red[16];
  if ((t & 63) == 0) red[t >> 6] = s;
  __syncthreads();
  if (t == 0) {
    float tot = 0.f;
    #pragma unroll
    for (int i2 = 0; i2 < 16; ++i2) tot += red[i2];
    out[0] = tot;
  }
}

extern "C" void kernel_launch(void* const* d_in, const int* in_sizes, int n_in,
                              void* d_out, int out_size, void* d_ws, size_t ws_size,
                              hipStream_t stream) {
  const float* resv = (const float*)d_in[0];
  const float* valv = (const float*)d_in[1];
  char* ws = (char*)d_ws;
  ushort_t* Qb    = (ushort_t*)ws;                 // 2,764,800 B
  ushort_t* Kb    = (ushort_t*)(ws + 2764800);     // 2,764,800 B
  float* qn       = (float*)(ws + 5529600);        //    57,600 B
  unsigned* rminb = (unsigned*)(ws + 5587200);     //    57,600 B
  float* out = (float*)d_out;

  prep_kernel<<<7200, 256, 0, stream>>>(resv, valv, Qb, Kb, qn, rminb);
  knn_kernel<<<1125, 256, 0, stream>>>(Qb, Kb, rminb);
  final_kernel<<<1, 1024, 0, stream>>>(rminb, qn, out);
}

// Round 8
// 55.098 us; speedup vs baseline: 1.1780x; 1.1780x over previous
//
#include <hip/hip_runtime.h>
#include <hip/hip_bf16.h>
#include <math.h>

typedef __attribute__((ext_vector_type(8))) short bf16x8;
typedef __attribute__((ext_vector_type(4))) float f32x4;
typedef unsigned short ushort_t;

#define NP 14400     // patches per video
#define NS 5         // column segments
#define NIT 45       // 64-col tiles per segment (45*64 = 2880 cols)
#define TILEB 12288  // bytes per 64-col tile (64 cols * 96 k * 2B)

__device__ __forceinline__ ushort_t f2bf(float f) {
  unsigned u = __float_as_uint(f);
  u += 0x7FFF + ((u >> 16) & 1);   // RNE
  return (ushort_t)(u >> 16);
}
__device__ __forceinline__ float bf2f(ushort_t b) {
  return __uint_as_float(((unsigned)b) << 16);
}

// Fragment-order layouts (16B chunks laid out so consumer reads are
// base + lane*16 + imm — fully coalesced, conflict-free):
// K: chunk = ((p>>6)*12 + ((p>>4)&3)*3 + (d>>5))*64 + ((d>>3)&3)*16 + (p&15)
// Q: chunk = ((p>>4)*3 + (d>>5))*64 + ((d>>3)&3)*16 + (p&15)
__device__ __forceinline__ size_t kidx(int p, int d) {
  return ((size_t)(((p >> 6) * 12 + ((p >> 4) & 3) * 3 + (d >> 5)) * 64
          + ((d >> 3) & 3) * 16 + (p & 15))) * 8 + (d & 7);
}
__device__ __forceinline__ size_t qidx(int p, int d) {
  return ((size_t)(((p >> 4) * 3 + (d >> 5)) * 64
          + ((d >> 3) & 3) * 16 + (p & 15))) * 8 + (d & 7);
}

// ---------------- prep: patches -> bf16 in fragment order -----------------
// Q: slots 0..74 = bf16(-2*q), 75,76 = 1.0, rest 0; qn = fp32 norm.
// K: slots 0..74 = bf16(k), 75 = bf16(kn), 76 = bf16(kn residual), rest 0.
// Also inits rminb to ordered-uint +inf (0xFFFFFFFF).
__global__ __launch_bounds__(256) void prep_kernel(
    const float* __restrict__ resv, const float* __restrict__ valv,
    ushort_t* __restrict__ Qb, ushort_t* __restrict__ Kb,
    float* __restrict__ qn, unsigned* __restrict__ rminb) {
  int w = threadIdx.x >> 6;
  int lane = threadIdx.x & 63;
  int pg = blockIdx.x * 4 + w;          // 0..28799
  int isK = pg >= NP;
  int p = isK ? pg - NP : pg;
  const float* src = isK ? valv : resv;
  int t = p / 3600; int rem = p - t * 3600;
  int y = rem / 60;  int x = rem - y * 60;

  float v0, v1 = 0.f;
  {
    int d = lane;  // < 75 always
    int c = d / 25; int r = d - c * 25; int dy = r / 5; int dx = r - dy * 5;
    v0 = src[((c * 4 + t) * 64 + (y + dy)) * 64 + (x + dx)];
  }
  if (lane < 11) {
    int d = lane + 64;
    int c = d / 25; int r = d - c * 25; int dy = r / 5; int dx = r - dy * 5;
    v1 = src[((c * 4 + t) * 64 + (y + dy)) * 64 + (x + dx)];
  }
  ushort_t b0 = f2bf(v0), b1 = f2bf(v1);
  float f0 = bf2f(b0), f1 = bf2f(b1);

  float sq = f0 * f0 + f1 * f1;
  #pragma unroll
  for (int off = 1; off < 64; off <<= 1) sq += __shfl_xor(sq, off, 64);

  if (isK) {
    ushort_t khi = f2bf(sq);
    ushort_t klo = f2bf(sq - bf2f(khi));
    ushort_t s1 = (lane < 11) ? b1
                : (lane == 11 ? khi : (lane == 12 ? klo : (ushort_t)0));
    Kb[kidx(p, lane)] = b0;
    if (lane < 32) Kb[kidx(p, lane + 64)] = s1;
  } else {
    ushort_t s0 = f2bf(-2.f * f0);
    ushort_t s1 = (lane < 11) ? f2bf(-2.f * f1)
                : ((lane == 11 || lane == 12) ? (ushort_t)0x3F80 : (ushort_t)0);
    Qb[qidx(p, lane)] = s0;
    if (lane < 32) Qb[qidx(p, lane + 64)] = s1;
    if (lane == 0) { qn[p] = sq; rminb[p] = 0xFFFFFFFFu; }
  }
}

// ------- main: wave-private 64x16 tiles, B streamed to VGPRs, depth-2 -----
__global__ __launch_bounds__(256, 4) void knn_kernel(
    const ushort_t* __restrict__ Qb, const ushort_t* __restrict__ Kb,
    unsigned* __restrict__ rminb) {
  // XCD-bijective swizzle: 1125 blocks, q=140 r=5; lin is ns-major so each
  // XCD sees one 0.55MB key segment + ~141 consecutive 64-row A blocks.
  int b = blockIdx.x;
  int xcd = b & 7, pos = b >> 3;
  int lin = (xcd < 5 ? xcd * 141 : 705 + (xcd - 5) * 140) + pos;
  int ns = lin / 225, rowblk = lin - ns * 225;
  int brow = rowblk * 64;
  int lane = threadIdx.x & 63;
  int w = threadIdx.x >> 6;
  int l15 = lane & 15, l4 = lane >> 4;

  // B stream base: fragment-order Kb; wave's 16-col slice of each 64-col
  // tile is 3 contiguous 1KB chunks (lane-contiguous 16B each).
  const char* gW = (const char*)Kb + (size_t)(ns * 45) * TILEB
                   + w * 3072 + lane * 16;

  // A fragments: 64 rows x 96 k, fragment-order Qb, lane-contiguous loads
  const char* Aw = (const char*)Qb + (size_t)(brow >> 4) * 3072 + lane * 16;
  bf16x8 af[4][3];
  #pragma unroll
  for (int rt = 0; rt < 4; ++rt)
    #pragma unroll
    for (int ks = 0; ks < 3; ++ks)
      af[rt][ks] = *(const bf16x8*)(Aw + (rt * 3 + ks) * 1024);

  float rmin[4][4];
  #pragma unroll
  for (int rt = 0; rt < 4; ++rt)
    #pragma unroll
    for (int j = 0; j < 4; ++j) rmin[rt][j] = INFINITY;

  const f32x4 fz = {0.f, 0.f, 0.f, 0.f};

  // depth-2 register rotation; all indices literal at every call site
  bf16x8 bbuf[2][3];

  auto loadB = [&](int bi, int it) {   // bi literal at call sites
    const char* g = gW + (size_t)it * TILEB;
    #pragma unroll
    for (int ks = 0; ks < 3; ++ks)
      bbuf[bi][ks] = *(const bf16x8*)(g + ks * 1024);
  };

  auto compute = [&](int bi) {         // bi literal at call sites
    f32x4 acc[4];
    {
      bf16x8 bv = bbuf[bi][0];
      #pragma unroll
      for (int rt = 0; rt < 4; ++rt)
        acc[rt] = __builtin_amdgcn_mfma_f32_16x16x32_bf16(af[rt][0], bv, fz, 0, 0, 0);
    }
    #pragma unroll
    for (int ks = 1; ks < 3; ++ks) {
      bf16x8 bv = bbuf[bi][ks];
      #pragma unroll
      for (int rt = 0; rt < 4; ++rt)
        acc[rt] = __builtin_amdgcn_mfma_f32_16x16x32_bf16(af[rt][ks], bv, acc[rt], 0, 0, 0);
    }
    #pragma unroll
    for (int rt = 0; rt < 4; ++rt)
      #pragma unroll
      for (int j = 0; j < 4; ++j)
        rmin[rt][j] = fminf(rmin[rt][j], acc[rt][j]);
  };

  loadB(0, 0);
  loadB(1, 1);

  // main loop: compute(b)[k] then immediately re-issue load into buf b for
  // k+2 (WAR-safe: MFMA reads operands at issue, which precedes the load in
  // program order). 21 doubles + 3-iter tail = 45.
  int k = 0;
  #pragma unroll 1
  for (int tri = 0; tri < 21; ++tri, k += 2) {
    compute(0); loadB(0, k + 2);
    compute(1); loadB(1, k + 3);
  }
  // k == 42; in flight: (0,42),(1,43)
  compute(0); loadB(0, 44);
  compute(1);
  compute(0);

  // min over the 16 key-cols (l15 lanes), then device atomicMin per row
  #pragma unroll
  for (int rt = 0; rt < 4; ++rt)
    #pragma unroll
    for (int j = 0; j < 4; ++j) {
      float m = rmin[rt][j];
      m = fminf(m, __shfl_xor(m, 1, 64));
      m = fminf(m, __shfl_xor(m, 2, 64));
      m = fminf(m, __shfl_xor(m, 4, 64));
      m = fminf(m, __shfl_xor(m, 8, 64));
      if (l15 == 0) {
        unsigned bu = __float_as_uint(m);
        unsigned tu = bu ^ (unsigned)(((int)bu >> 31) | (int)0x80000000);
        atomicMin(&rminb[brow + rt * 16 + l4 * 4 + j], tu);
      }
    }
}

// ------ final stage 1: decode + add qn, per-block partial sums ------------
__global__ __launch_bounds__(64) void final1_kernel(
    const unsigned* __restrict__ rminb, const float* __restrict__ qn,
    float* __restrict__ partial) {
  int r = blockIdx.x * 64 + threadIdx.x;   // grid 225 covers 14400
  unsigned u = rminb[r];
  unsigned bu = (u & 0x80000000u) ? (u ^ 0x80000000u) : ~u;
  float val = __uint_as_float(bu) + qn[r];
  #pragma unroll
  for (int off = 32; off; off >>= 1) val += __shfl_down(val, off, 64);
  if (threadIdx.x == 0) partial[blockIdx.x] = val;
}

// ------ final stage 2: deterministic sum of 225 partials ------------------
__global__ __launch_bounds__(256) void final2_kernel(
    const float* __restrict__ partial, float* __restrict__ out) {
  int t = threadIdx.x;
  float v = (t < 225) ? partial[t] : 0.f;
  #pragma unroll
  for (int off = 32; off; off >>= 1) v += __shfl_down(v, off, 64);
  __shared__ float s[4];
  if ((t & 63) == 0) s[t >> 6] = v;
  __syncthreads();
  if (t == 0) out[0] = s[0] + s[1] + s[2] + s[3];
}

extern "C" void kernel_launch(void* const* d_in, const int* in_sizes, int n_in,
                              void* d_out, int out_size, void* d_ws, size_t ws_size,
                              hipStream_t stream) {
  const float* resv = (const float*)d_in[0];
  const float* valv = (const float*)d_in[1];
  char* ws = (char*)d_ws;
  ushort_t* Qb    = (ushort_t*)ws;                 // 2,764,800 B
  ushort_t* Kb    = (ushort_t*)(ws + 2764800);     // 2,764,800 B
  float* qn       = (float*)(ws + 5529600);        //    57,600 B
  unsigned* rminb = (unsigned*)(ws + 5587200);     //    57,600 B
  float* partial  = (float*)(ws + 5644800);        //       900 B
  float* out = (float*)d_out;

  prep_kernel<<<7200, 256, 0, stream>>>(resv, valv, Qb, Kb, qn, rminb);
  knn_kernel<<<1125, 256, 0, stream>>>(Qb, Kb, rminb);
  final1_kernel<<<225, 64, 0, stream>>>(rminb, qn, partial);
  final2_kernel<<<1, 256, 0, stream>>>(partial, out);
}